// Round 2
// baseline (3624.519 us; speedup 1.0000x reference)
//
#include <hip/hip_runtime.h>

#define B 8
#define N 8192
#define S 2048
#define K 32
#define TPB 512          // FPS threads/block (8 waves)
#define PPT (N / TPB)    // 16 points per thread

// Exact (no-FMA, left-to-right) squared distance to match numpy/XLA fp32:
// ((dx*dx + dy*dy) + dz*dz). FPS argmax is a chaotic recurrence; any ulp
// difference can diverge the selected-center sequence. Verified absmax==0 (R1).
__device__ __forceinline__ float sqdist3(float ax, float ay, float az,
                                         float bx, float by, float bz) {
    float dx = ax - bx, dy = ay - by, dz = az - bz;
    return __fadd_rn(__fadd_rn(__fmul_rn(dx, dx), __fmul_rn(dy, dy)),
                     __fmul_rn(dz, dz));
}

// ---------------------------------------------------------------------------
// FPS: one block per batch, 512 threads, 16 points/thread in registers.
// ONE barrier per step (R1 had 3 + LDS atomicMin; barrier latency was ~75%
// of the 3240 cyc/step). Packed key (dist_bits<<32)|(~idx): single u64
// max-reduce gives argmax + first-index tie-break (keys unique per point).
// Winner coords ride per-wave LDS slots; every thread rebuilds (px,py,pz)
// after the single barrier. LDS double-buffered so step s+2's write can't
// race step s's read.
// ---------------------------------------------------------------------------
__global__ __launch_bounds__(TPB) void fps_kernel(const float* __restrict__ xyz,
                                                  float* __restrict__ centers) {
    const int b = blockIdx.x;
    const float* xb = xyz + (size_t)b * N * 3;
    const int t = threadIdx.x;

    float x[PPT], y[PPT], z[PPT], md[PPT];
#pragma unroll
    for (int i = 0; i < PPT; ++i) {
        const int p = t + (i << 9);       // coalesced: stride-512
        x[i] = xb[3 * p + 0];
        y[i] = xb[3 * p + 1];
        z[i] = xb[3 * p + 2];
        md[i] = INFINITY;
    }

    __shared__ unsigned long long kbuf[2][8];
    __shared__ float xbuf[2][8], ybuf[2][8], zbuf[2][8];

    // step 0: reference always picks index 0 first (broadcast load, all lanes)
    float px = xb[0], py = xb[1], pz = xb[2];
    float* cb = centers + (size_t)b * S * 3;
    if (t == 0) { cb[0] = px; cb[1] = py; cb[2] = pz; }

    const int wid = t >> 6;
    for (int s = 1; s < S; ++s) {
        // --- local update + local argmax (strict > keeps smallest i => smallest idx)
        float best = -INFINITY;
        int bi = 0;
#pragma unroll
        for (int i = 0; i < PPT; ++i) {
            const float d = sqdist3(x[i], y[i], z[i], px, py, pz);
            const float m = fminf(md[i], d);
            md[i] = m;
            if (m > best) { best = m; bi = i; }
        }
        const unsigned gid = (unsigned)(t + (bi << 9));
        const unsigned long long key =
            ((unsigned long long)__float_as_uint(best) << 32) |
            (unsigned)(0xFFFFFFFFu - gid);   // max key = max dist, tie -> min idx

        // --- wave max of packed key (6 levels)
        unsigned long long wkey = key;
#pragma unroll
        for (int o = 1; o < 64; o <<= 1) {
            const unsigned long long ok = __shfl_xor(wkey, o);
            wkey = (ok > wkey) ? ok : wkey;
        }

        // --- unique owner lane per wave publishes key + coords
        const int pb = s & 1;
        if (key == wkey) {
            kbuf[pb][wid] = wkey;
            xbuf[pb][wid] = x[bi];
            ybuf[pb][wid] = y[bi];
            zbuf[pb][wid] = z[bi];
        }
        __syncthreads();                     // the ONLY barrier per step

        // --- every thread scans the 8 wave winners (broadcast LDS reads)
        unsigned long long gkey = kbuf[pb][0];
        int w_ = 0;
#pragma unroll
        for (int w = 1; w < 8; ++w) {
            const unsigned long long kk = kbuf[pb][w];
            if (kk > gkey) { gkey = kk; w_ = w; }
        }
        px = xbuf[pb][w_];
        py = ybuf[pb][w_];
        pz = zbuf[pb][w_];

        // --- unique global owner writes the center (from registers, fire&forget)
        if (key == gkey) {
            float* c = cb + 3 * s;
            c[0] = x[bi]; c[1] = y[bi]; c[2] = z[bi];
        }
    }
}

// ---------------------------------------------------------------------------
// KNN + gather: one wave per center. Top-32 held SORTED across lanes 0..31 as
// packed u64 (dist_bits<<32 | idx) -> lexicographic (d, idx) order == stable
// top_k tie semantics. Insert = wave-wide shfl_up shift (O(1) per insert).
// ---------------------------------------------------------------------------
__global__ __launch_bounds__(256) void knn_kernel(const float* __restrict__ xyz,
                                                  const float* __restrict__ centers,
                                                  float* __restrict__ out) {
    const int gw = (int)((blockIdx.x * blockDim.x + threadIdx.x) >> 6);
    const int lane = (int)(threadIdx.x & 63);
    const int b = gw >> 11;        // gw / S
    const int s = gw & (S - 1);
    const float* xb = xyz + (size_t)b * N * 3;
    const float* c = centers + (size_t)(b * S + s) * 3;
    const float cx = c[0], cy = c[1], cz = c[2];

    unsigned long long P = ~0ULL;     // lanes 0..31: sorted top-32 (asc)
    unsigned long long tau = ~0ULL;   // current worst kept = P at lane 31

    for (int i = 0; i < N / 64; ++i) {
        const int p = (i << 6) + lane;
        const float* q = xb + 3 * p;
        const float d = sqdist3(q[0], q[1], q[2], cx, cy, cz);
        const unsigned long long cand =
            ((unsigned long long)__float_as_uint(d) << 32) | (unsigned)p;
        bool alive = cand < tau;
        unsigned long long mask = __ballot(alive);
        while (mask) {
            const int src = __builtin_ctzll(mask);
            const unsigned long long bc = __shfl(cand, src);
            unsigned long long up = __shfl_up(P, 1);
            if (lane == 0) up = bc;
            const bool gt = P > bc;  // strict: bc < tau guarantees lane31 evicts
            const unsigned long long shifted = (up > bc) ? up : bc;
            P = gt ? shifted : P;
            tau = __shfl(P, 31);
            if (lane == src) alive = false;
            alive = alive && (cand < tau);
            mask = __ballot(alive);
        }
    }

    // epilogue: lane k = k-th nearest (ascending d, ties by index = top_k order)
    if (lane < K) {
        const unsigned nidx = (unsigned)P;
        const float* q = xb + 3 * nidx;
        float* o = out + ((size_t)(b * S + s) * K + lane) * 3;
        o[0] = q[0] - cx;
        o[1] = q[1] - cy;
        o[2] = q[2] - cz;
    }
}

extern "C" void kernel_launch(void* const* d_in, const int* in_sizes, int n_in,
                              void* d_out, int out_size, void* d_ws, size_t ws_size,
                              hipStream_t stream) {
    const float* xyz = (const float*)d_in[0];
    float* out = (float*)d_out;                         // neighborhood [B,S,K,3]
    float* centers = out + (size_t)B * S * K * 3;       // centers [B,S,3]

    fps_kernel<<<B, TPB, 0, stream>>>(xyz, centers);
    knn_kernel<<<(B * S) / 4, 256, 0, stream>>>(xyz, centers, out);
}

// Round 3
// 2955.286 us; speedup vs baseline: 1.2265x; 1.2265x over previous
//
#include <hip/hip_runtime.h>

#define B 8
#define N 8192
#define S 2048
#define K 32
#define TPB 512          // FPS threads/block (8 waves)
#define PPT (N / TPB)    // 16 contiguous points per thread: gid = t*16 + i

// Exact (no-FMA, left-to-right) squared distance to match numpy/XLA fp32:
// ((dx*dx + dy*dy) + dz*dz). FPS argmax is a chaotic recurrence; any ulp
// difference can diverge the selected-center sequence. Verified absmax==0 (R1/R2).
__device__ __forceinline__ float sqdist3(float ax, float ay, float az,
                                         float bx, float by, float bz) {
    float dx = ax - bx, dy = ay - by, dz = az - bz;
    return __fadd_rn(__fadd_rn(__fmul_rn(dx, dx), __fmul_rn(dy, dy)),
                     __fmul_rn(dz, dz));
}

// DPP max: VALU-latency cross-lane (vs ds_bpermute-based __shfl ~LDS latency).
// bound_ctrl=false + old=v -> invalid source lanes contribute v (harmless).
template <int CTRL>
__device__ __forceinline__ float dpp_fmax(float v) {
    const int iv = __float_as_int(v);
    const int sh = __builtin_amdgcn_update_dpp(iv, iv, CTRL, 0xF, 0xF, false);
    return fmaxf(v, __int_as_float(sh));
}

// Full-wave (64 lane) max via DPP prefix: rows of 16, then bcast15/31.
// Result valid in lane 63; broadcast via readlane.
__device__ __forceinline__ float wave_fmax_dpp(float v) {
    v = dpp_fmax<0x111>(v);  // row_shr:1
    v = dpp_fmax<0x112>(v);  // row_shr:2
    v = dpp_fmax<0x114>(v);  // row_shr:4
    v = dpp_fmax<0x118>(v);  // row_shr:8  -> lane 15 of each row = row max
    v = dpp_fmax<0x142>(v);  // row_bcast:15 -> lane 31 = max(rows 0,1); 63 = max(2,3)
    v = dpp_fmax<0x143>(v);  // row_bcast:31 -> lane 63 = wave max
    return __int_as_float(__builtin_amdgcn_readlane(__float_as_int(v), 63));
}

// ---------------------------------------------------------------------------
// FPS: one block per batch, 512 threads, 16 CONTIGUOUS points per thread in
// registers. One barrier per step. Wave argmax = f32 DPP max-reduce + ballot
// first-set-lane (contiguous gid mapping makes (wave,lane,i) order == gid
// order, so ballot+ctz IS the first-index tie-break). Winner coords ride
// per-wave LDS slots, double-buffered (no second barrier needed).
// ---------------------------------------------------------------------------
__global__ __launch_bounds__(TPB) void fps_kernel(const float* __restrict__ xyz,
                                                  float* __restrict__ centers) {
    const int b = blockIdx.x;
    const float* xb = xyz + (size_t)b * N * 3;
    const int t = threadIdx.x;

    // load 16 contiguous points (48 floats = 12 float4, 16B-aligned: 192B*t)
    float raw[3 * PPT];
    const float4* src = (const float4*)(xb + 3 * PPT * t);
#pragma unroll
    for (int i = 0; i < 3 * PPT / 4; ++i) {
        const float4 v = src[i];
        raw[4 * i + 0] = v.x; raw[4 * i + 1] = v.y;
        raw[4 * i + 2] = v.z; raw[4 * i + 3] = v.w;
    }
    float x[PPT], y[PPT], z[PPT], md[PPT];
#pragma unroll
    for (int i = 0; i < PPT; ++i) {
        x[i] = raw[3 * i + 0];
        y[i] = raw[3 * i + 1];
        z[i] = raw[3 * i + 2];
        md[i] = INFINITY;
    }

    __shared__ float kbuf[2][8];
    __shared__ float cxb[2][8], cyb[2][8], czb[2][8];

    // step 0: reference always picks point 0 (broadcast load, all lanes)
    float px = xb[0], py = xb[1], pz = xb[2];
    float* cb = centers + (size_t)b * S * 3;
    if (t == 0) { cb[0] = px; cb[1] = py; cb[2] = pz; }

    const int wid = t >> 6;
    const int lane = t & 63;
    for (int s = 1; s < S; ++s) {
        // --- local update + local argmax (strict >, ascending i -> first idx)
        float best = -INFINITY;
        int bi = 0;
#pragma unroll
        for (int i = 0; i < PPT; ++i) {
            const float d = sqdist3(x[i], y[i], z[i], px, py, pz);
            const float m = fminf(md[i], d);
            md[i] = m;
            if (m > best) { best = m; bi = i; }
        }

        // --- wave max (DPP, ~60 cyc chain) + first-lane tie-break via ballot
        const float wmax = wave_fmax_dpp(best);
        const unsigned long long mb = __ballot(best == wmax);
        const int ol = (int)__builtin_ctzll(mb);   // lowest lane == lowest gid

        // --- wave owner publishes value + coords to this step's buffer
        const int pb = s & 1;
        if (lane == ol) {
            kbuf[pb][wid] = wmax;
            cxb[pb][wid] = x[bi];
            cyb[pb][wid] = y[bi];
            czb[pb][wid] = z[bi];
        }
        __syncthreads();                           // the ONLY barrier per step

        // --- every thread scans the 8 wave winners (broadcast LDS reads;
        //     strict > keeps lowest wid == lowest gid on ties)
        float gmax = kbuf[pb][0];
        int w_ = 0;
#pragma unroll
        for (int w = 1; w < 8; ++w) {
            const float kk = kbuf[pb][w];
            if (kk > gmax) { gmax = kk; w_ = w; }
        }
        px = cxb[pb][w_];
        py = cyb[pb][w_];
        pz = czb[pb][w_];

        // --- unique global owner writes the center (from registers)
        if (wid == w_ && lane == ol) {
            float* c = cb + 3 * s;
            c[0] = x[bi]; c[1] = y[bi]; c[2] = z[bi];
        }
    }
}

// ---------------------------------------------------------------------------
// KNN + gather: one wave per center. Top-32 held SORTED across lanes 0..31 as
// packed u64 (dist_bits<<32 | idx) -> lexicographic (d, idx) order == stable
// top_k tie semantics. Insert = wave-wide shfl_up shift (O(1) per insert).
// ---------------------------------------------------------------------------
__global__ __launch_bounds__(256) void knn_kernel(const float* __restrict__ xyz,
                                                  const float* __restrict__ centers,
                                                  float* __restrict__ out) {
    const int gw = (int)((blockIdx.x * blockDim.x + threadIdx.x) >> 6);
    const int lane = (int)(threadIdx.x & 63);
    const int b = gw >> 11;        // gw / S
    const int s = gw & (S - 1);
    const float* xb = xyz + (size_t)b * N * 3;
    const float* c = centers + (size_t)(b * S + s) * 3;
    const float cx = c[0], cy = c[1], cz = c[2];

    unsigned long long P = ~0ULL;     // lanes 0..31: sorted top-32 (asc)
    unsigned long long tau = ~0ULL;   // current worst kept = P at lane 31

    for (int i = 0; i < N / 64; ++i) {
        const int p = (i << 6) + lane;
        const float* q = xb + 3 * p;
        const float d = sqdist3(q[0], q[1], q[2], cx, cy, cz);
        const unsigned long long cand =
            ((unsigned long long)__float_as_uint(d) << 32) | (unsigned)p;
        bool alive = cand < tau;
        unsigned long long mask = __ballot(alive);
        while (mask) {
            const int src = __builtin_ctzll(mask);
            const unsigned long long bc = __shfl(cand, src);
            unsigned long long up = __shfl_up(P, 1);
            if (lane == 0) up = bc;
            const bool gt = P > bc;  // strict: bc < tau guarantees lane31 evicts
            const unsigned long long shifted = (up > bc) ? up : bc;
            P = gt ? shifted : P;
            tau = __shfl(P, 31);
            if (lane == src) alive = false;
            alive = alive && (cand < tau);
            mask = __ballot(alive);
        }
    }

    // epilogue: lane k = k-th nearest (ascending d, ties by index = top_k order)
    if (lane < K) {
        const unsigned nidx = (unsigned)P;
        const float* q = xb + 3 * nidx;
        float* o = out + ((size_t)(b * S + s) * K + lane) * 3;
        o[0] = q[0] - cx;
        o[1] = q[1] - cy;
        o[2] = q[2] - cz;
    }
}

extern "C" void kernel_launch(void* const* d_in, const int* in_sizes, int n_in,
                              void* d_out, int out_size, void* d_ws, size_t ws_size,
                              hipStream_t stream) {
    const float* xyz = (const float*)d_in[0];
    float* out = (float*)d_out;                         // neighborhood [B,S,K,3]
    float* centers = out + (size_t)B * S * K * 3;       // centers [B,S,3]

    fps_kernel<<<B, TPB, 0, stream>>>(xyz, centers);
    knn_kernel<<<(B * S) / 4, 256, 0, stream>>>(xyz, centers, out);
}

// Round 4
// 2698.892 us; speedup vs baseline: 1.3430x; 1.0950x over previous
//
#include <hip/hip_runtime.h>

#define B 8
#define N 8192
#define S 2048
#define K 32
#define TPB 512          // FPS threads/block (8 waves)
#define PPT (N / TPB)    // 16 contiguous points per thread: gid = t*16 + i

// Exact (no-FMA, left-to-right) squared distance to match numpy/XLA fp32:
// ((dx*dx + dy*dy) + dz*dz). FPS argmax is a chaotic recurrence; any ulp
// difference can diverge the selected-center sequence. Verified absmax==0 (R1-R3).
__device__ __forceinline__ float sqdist3(float ax, float ay, float az,
                                         float bx, float by, float bz) {
    float dx = ax - bx, dy = ay - by, dz = az - bz;
    return __fadd_rn(__fadd_rn(__fmul_rn(dx, dx), __fmul_rn(dy, dy)),
                     __fmul_rn(dz, dz));
}

// DPP max: VALU-latency cross-lane (vs ds_bpermute-based __shfl ~LDS latency).
template <int CTRL>
__device__ __forceinline__ float dpp_fmax(float v) {
    const int iv = __float_as_int(v);
    const int sh = __builtin_amdgcn_update_dpp(iv, iv, CTRL, 0xF, 0xF, false);
    return fmaxf(v, __int_as_float(sh));
}

// Full-wave (64 lane) max via DPP; result broadcast from lane 63.
__device__ __forceinline__ float wave_fmax_dpp(float v) {
    v = dpp_fmax<0x111>(v);  // row_shr:1
    v = dpp_fmax<0x112>(v);  // row_shr:2
    v = dpp_fmax<0x114>(v);  // row_shr:4
    v = dpp_fmax<0x118>(v);  // row_shr:8
    v = dpp_fmax<0x142>(v);  // row_bcast:15
    v = dpp_fmax<0x143>(v);  // row_bcast:31 -> lane 63 = wave max
    return __int_as_float(__builtin_amdgcn_readlane(__float_as_int(v), 63));
}

// ---------------------------------------------------------------------------
// FPS: one block per batch, 512 threads, 16 CONTIGUOUS points/thread in regs.
// Loop-body invariants vs R3:
//  - ZERO global memory ops inside the step loop (centers buffered in LDS,
//    dumped coalesced at the end) -> barrier's vmcnt(0) drain is free.
//  - One barrier/step; publish is a single float4 {wmax,x,y,z} per wave ->
//    post-barrier = 8 independent broadcast ds_read_b128 + register scan
//    (no dependent second LDS read).
//  - Local argmax = fmaxf tree (15 ops); owner lane re-derives bi in its
//    masked path (descending overwrite keeps first/lowest index).
// Selection order identical to R1-R3: (max dist, then lowest gid).
// ---------------------------------------------------------------------------
__global__ __launch_bounds__(TPB) void fps_kernel(const float* __restrict__ xyz,
                                                  float* __restrict__ centers) {
    const int b = blockIdx.x;
    const float* xb = xyz + (size_t)b * N * 3;
    const int t = threadIdx.x;

    // load 16 contiguous points (48 floats = 12 float4, 16B-aligned: 192B*t)
    float raw[3 * PPT];
    const float4* src = (const float4*)(xb + 3 * PPT * t);
#pragma unroll
    for (int i = 0; i < 3 * PPT / 4; ++i) {
        const float4 v = src[i];
        raw[4 * i + 0] = v.x; raw[4 * i + 1] = v.y;
        raw[4 * i + 2] = v.z; raw[4 * i + 3] = v.w;
    }
    float x[PPT], y[PPT], z[PPT], md[PPT];
#pragma unroll
    for (int i = 0; i < PPT; ++i) {
        x[i] = raw[3 * i + 0];
        y[i] = raw[3 * i + 1];
        z[i] = raw[3 * i + 2];
        md[i] = INFINITY;
    }

    __shared__ float4 pub[2][8];        // per-wave {wmax, x, y, z}, dbuf
    __shared__ float cent[S * 3];       // centers staged in LDS (24 KB)

    // step 0: reference always picks point 0
    float px = xb[0], py = xb[1], pz = xb[2];
    if (t == 0) { cent[0] = px; cent[1] = py; cent[2] = pz; }

    const int wid = t >> 6;
    const int lane = t & 63;
    for (int s = 1; s < S; ++s) {
        // --- local update; best = tree max (log-depth, no index tracking)
        float m[PPT];
#pragma unroll
        for (int i = 0; i < PPT; ++i) {
            const float d = sqdist3(x[i], y[i], z[i], px, py, pz);
            m[i] = fminf(md[i], d);
            md[i] = m[i];
        }
#pragma unroll
        for (int st = 1; st < PPT; st <<= 1)
#pragma unroll
            for (int i = 0; i < PPT; i += 2 * st)
                m[i] = fmaxf(m[i], m[i + st]);
        const float best = m[0];

        // --- wave max (DPP) + first-lane tie-break via ballot
        const float wmax = wave_fmax_dpp(best);
        const unsigned long long mb = __ballot(best == wmax);
        const int ol = (int)__builtin_ctzll(mb);   // lowest lane == lowest gid

        // --- wave owner: re-derive bi (descending overwrite -> lowest i),
        //     publish {wmax, coords} as one b128 write
        const int pb = s & 1;
        if (lane == ol) {
            int bi = 0;
#pragma unroll
            for (int i = PPT - 1; i >= 0; --i)
                if (md[i] == wmax) bi = i;
            pub[pb][wid] = make_float4(wmax, x[bi], y[bi], z[bi]);
        }
        __syncthreads();                           // no vmcnt to drain now

        // --- scan 8 wave winners (independent broadcast b128 reads)
        float4 v0 = pub[pb][0];
        float gmax = v0.x;
        px = v0.y; py = v0.z; pz = v0.w;
#pragma unroll
        for (int w = 1; w < 8; ++w) {
            const float4 u = pub[pb][w];
            const bool g = u.x > gmax;             // strict: lowest wid wins ties
            gmax = g ? u.x : gmax;
            px = g ? u.y : px;
            py = g ? u.z : py;
            pz = g ? u.w : pz;
        }

        // --- winner coords already in every thread's registers; t0 stages them
        if (t == 0) {
            cent[3 * s + 0] = px;
            cent[3 * s + 1] = py;
            cent[3 * s + 2] = pz;
        }
    }

    // --- coalesced dump of centers LDS -> global (S*3 = 6144 = 512*12)
    __syncthreads();
    float* cb = centers + (size_t)b * S * 3;
#pragma unroll
    for (int j = 0; j < (S * 3) / TPB; ++j) {
        const int idx = t + TPB * j;
        cb[idx] = cent[idx];
    }
}

// ---------------------------------------------------------------------------
// KNN + gather: one wave per center. Top-32 held SORTED across lanes 0..31 as
// packed u64 (dist_bits<<32 | idx) -> lexicographic (d, idx) order == stable
// top_k tie semantics. Insert = wave-wide shfl_up shift (O(1) per insert).
// ---------------------------------------------------------------------------
__global__ __launch_bounds__(256) void knn_kernel(const float* __restrict__ xyz,
                                                  const float* __restrict__ centers,
                                                  float* __restrict__ out) {
    const int gw = (int)((blockIdx.x * blockDim.x + threadIdx.x) >> 6);
    const int lane = (int)(threadIdx.x & 63);
    const int b = gw >> 11;        // gw / S
    const int s = gw & (S - 1);
    const float* xb = xyz + (size_t)b * N * 3;
    const float* c = centers + (size_t)(b * S + s) * 3;
    const float cx = c[0], cy = c[1], cz = c[2];

    unsigned long long P = ~0ULL;     // lanes 0..31: sorted top-32 (asc)
    unsigned long long tau = ~0ULL;   // current worst kept = P at lane 31

    for (int i = 0; i < N / 64; ++i) {
        const int p = (i << 6) + lane;
        const float* q = xb + 3 * p;
        const float d = sqdist3(q[0], q[1], q[2], cx, cy, cz);
        const unsigned long long cand =
            ((unsigned long long)__float_as_uint(d) << 32) | (unsigned)p;
        bool alive = cand < tau;
        unsigned long long mask = __ballot(alive);
        while (mask) {
            const int src = __builtin_ctzll(mask);
            const unsigned long long bc = __shfl(cand, src);
            unsigned long long up = __shfl_up(P, 1);
            if (lane == 0) up = bc;
            const bool gt = P > bc;  // strict: bc < tau guarantees lane31 evicts
            const unsigned long long shifted = (up > bc) ? up : bc;
            P = gt ? shifted : P;
            tau = __shfl(P, 31);
            if (lane == src) alive = false;
            alive = alive && (cand < tau);
            mask = __ballot(alive);
        }
    }

    // epilogue: lane k = k-th nearest (ascending d, ties by index = top_k order)
    if (lane < K) {
        const unsigned nidx = (unsigned)P;
        const float* q = xb + 3 * nidx;
        float* o = out + ((size_t)(b * S + s) * K + lane) * 3;
        o[0] = q[0] - cx;
        o[1] = q[1] - cy;
        o[2] = q[2] - cz;
    }
}

extern "C" void kernel_launch(void* const* d_in, const int* in_sizes, int n_in,
                              void* d_out, int out_size, void* d_ws, size_t ws_size,
                              hipStream_t stream) {
    const float* xyz = (const float*)d_in[0];
    float* out = (float*)d_out;                         // neighborhood [B,S,K,3]
    float* centers = out + (size_t)B * S * K * 3;       // centers [B,S,3]

    fps_kernel<<<B, TPB, 0, stream>>>(xyz, centers);
    knn_kernel<<<(B * S) / 4, 256, 0, stream>>>(xyz, centers, out);
}